// Round 6
// baseline (357.526 us; speedup 1.0000x reference)
//
#include <hip/hip_runtime.h>
#include <hip/hip_bf16.h>

// LightGCN forward: x0 = concat(user_emb, item_emb); 3x { x = A*x }; out = (x0+x1+x2+x3)/4.
// Sorted COO -> CSR row_ptr (binary search). Edges pre-expanded into a PADDED
// array pe[]: row r's segment starts at row_ptr[r] + 16*r (capacity deg+16),
// entry = {byte offset col*128, val fp32}, zero-padded to a multiple of 16
// -> branchless hot loop. SpMM: one wave per row, QUARTER-wave per edge
// (16 lanes x 4 dims via dwordx2): one gather instr covers 4 edges, 16 edges
// unrolled per step for MLP. pe entries broadcast via coalesced same-address
// global loads (no LDS stage, no shfl). Layer 3 fused with mean epilogue.

#define EMB 64

typedef unsigned short u16;
typedef unsigned int   u32;

__device__ __forceinline__ u16 f2bf(float f) {      // round-to-nearest-even
    u32 u = __float_as_uint(f);
    return (u16)((u + 0x7FFFu + ((u >> 16) & 1u)) >> 16);
}
__device__ __forceinline__ float bflo(u32 p) { return __uint_as_float(p << 16); }
__device__ __forceinline__ float bfhi(u32 p) { return __uint_as_float(p & 0xFFFF0000u); }

__global__ void init_x_kernel(const float4* __restrict__ user,
                              const float4* __restrict__ item,
                              ushort4* __restrict__ x,
                              int n_user_vec, int n_total_vec) {
    int i = blockIdx.x * blockDim.x + threadIdx.x;
    if (i >= n_total_vec) return;
    float4 v = (i < n_user_vec) ? user[i] : item[i - n_user_vec];
    ushort4 o;
    o.x = f2bf(v.x); o.y = f2bf(v.y); o.z = f2bf(v.z); o.w = f2bf(v.w);
    x[i] = o;
}

// row_ptr[r] = lower_bound(rows, r); rows sorted.
__global__ void build_row_ptr_kernel(const int* __restrict__ rows, int nnz,
                                     int n_rows, int* __restrict__ row_ptr) {
    int r = blockIdx.x * blockDim.x + threadIdx.x;
    if (r > n_rows) return;
    int lo = 0, hi = nnz;
    while (lo < hi) {
        int mid = (lo + hi) >> 1;
        if (rows[mid] < r) lo = mid + 1; else hi = mid;
    }
    row_ptr[r] = lo;
}

// pe[e + 16*rows[e]] = {cols[e]*128, vals[e]}; last edge of each row zero-fills
// the <=15 pad slots up to the row's ceil16(deg) boundary.
__global__ void expand_kernel(const int* __restrict__ rows,
                              const int* __restrict__ cols,
                              const float* __restrict__ vals,
                              const int* __restrict__ row_ptr,
                              int nnz, int2* __restrict__ pe) {
    int e = blockIdx.x * blockDim.x + threadIdx.x;
    if (e >= nnz) return;
    int r = rows[e];
    int dst = e + 16 * r;
    int2 ent;
    ent.x = cols[e] << 7;                    // byte offset into bf16 x table
    ent.y = __float_as_int(vals[e]);
    pe[dst] = ent;
    bool last = (e == nnz - 1) || (rows[e + 1] != r);
    if (last) {
        int s   = row_ptr[r];
        int deg = e + 1 - s;
        int cnt = (deg + 15) & ~15;
        int lim = s + 16 * r + cnt;          // segment start + padded count
        int2 z; z.x = 0; z.y = 0;
        for (int j = dst + 1; j < lim; ++j) pe[j] = z;
    }
}

// Core accumulate: one wave per row, quarter q handles edges {j+4k+q}.
// Returns 4 dims per lane (dims 4*sub .. 4*sub+3) after cross-quarter reduce.
__device__ __forceinline__ void spmm_row(const int2* __restrict__ pe,
                                         const char* __restrict__ xb,
                                         int ps, int cnt, int q, u32 lane_byte,
                                         float& a0, float& a1, float& a2, float& a3) {
    a0 = a1 = a2 = a3 = 0.0f;
    int pq = ps + q;
    for (int j = 0; j < cnt; j += 16) {
        int2 ent[4];
#pragma unroll
        for (int k = 0; k < 4; ++k)
            ent[k] = pe[pq + j + 4 * k];       // 16 same-addr lanes -> 1 req
        uint2 xp[4];
#pragma unroll
        for (int k = 0; k < 4; ++k)
            xp[k] = *(const uint2*)(xb + ((u32)ent[k].x + lane_byte));
#pragma unroll
        for (int k = 0; k < 4; ++k) {
            float v = __int_as_float(ent[k].y);
            a0 = fmaf(v, bflo(xp[k].x), a0);
            a1 = fmaf(v, bfhi(xp[k].x), a1);
            a2 = fmaf(v, bflo(xp[k].y), a2);
            a3 = fmaf(v, bfhi(xp[k].y), a3);
        }
    }
    a0 += __shfl_xor(a0, 16); a1 += __shfl_xor(a1, 16);
    a2 += __shfl_xor(a2, 16); a3 += __shfl_xor(a3, 16);
    a0 += __shfl_xor(a0, 32); a1 += __shfl_xor(a1, 32);
    a2 += __shfl_xor(a2, 32); a3 += __shfl_xor(a3, 32);
}

__global__ void spmm_kernel(const int* __restrict__ row_ptr,
                            const int2* __restrict__ pe,
                            const u32* __restrict__ x,    // bf16x2 table [n*32]
                            u32* __restrict__ y,          // bf16x2 out   [n*32]
                            int n_rows) {
    int lane = threadIdx.x & 63;
    int sub  = lane & 15;
    int q    = lane >> 4;
    int wid  = blockIdx.x * 4 + (threadIdx.x >> 6);
    if (wid >= n_rows) return;

    int s   = row_ptr[wid];
    int deg = row_ptr[wid + 1] - s;
    int cnt = (deg + 15) & ~15;
    int ps  = s + 16 * wid;

    float a0, a1, a2, a3;
    spmm_row(pe, (const char*)x, ps, cnt, q, (u32)sub * 8u, a0, a1, a2, a3);

    if (q == 0) {
        uint2 w;
        w.x = ((u32)f2bf(a1) << 16) | (u32)f2bf(a0);
        w.y = ((u32)f2bf(a3) << 16) | (u32)f2bf(a2);
        *(uint2*)&y[(size_t)wid * 32 + sub * 2] = w;
    }
}

// Layer 3 fused with epilogue: out = (x0 + y1 + y2 + A*y2) * 0.25 (fp32 out).
__global__ void spmm_final_kernel(const int* __restrict__ row_ptr,
                                  const int2* __restrict__ pe,
                                  const u32* __restrict__ x0,   // bf16x2 [n*32]
                                  const u32* __restrict__ y1,
                                  const u32* __restrict__ y2,   // also gather src
                                  float4* __restrict__ out,     // [n*16]
                                  int n_rows) {
    int lane = threadIdx.x & 63;
    int sub  = lane & 15;
    int q    = lane >> 4;
    int wid  = blockIdx.x * 4 + (threadIdx.x >> 6);
    if (wid >= n_rows) return;

    int s   = row_ptr[wid];
    int deg = row_ptr[wid + 1] - s;
    int cnt = (deg + 15) & ~15;
    int ps  = s + 16 * wid;

    float a0, a1, a2, a3;
    spmm_row(pe, (const char*)y2, ps, cnt, q, (u32)sub * 8u, a0, a1, a2, a3);

    if (q == 0) {
        size_t i2 = (size_t)wid * 32 + sub * 2;
        u32 x00 = x0[i2], x01 = x0[i2 + 1];
        u32 p10 = y1[i2], p11 = y1[i2 + 1];
        u32 p20 = y2[i2], p21 = y2[i2 + 1];
        float4 r;
        r.x = (bflo(x00) + bflo(p10) + bflo(p20) + a0) * 0.25f;
        r.y = (bfhi(x00) + bfhi(p10) + bfhi(p20) + a1) * 0.25f;
        r.z = (bflo(x01) + bflo(p11) + bflo(p21) + a2) * 0.25f;
        r.w = (bfhi(x01) + bfhi(p11) + bfhi(p21) + a3) * 0.25f;
        out[(size_t)wid * 16 + sub] = r;
    }
}

extern "C" void kernel_launch(void* const* d_in, const int* in_sizes, int n_in,
                              void* d_out, int out_size, void* d_ws, size_t ws_size,
                              hipStream_t stream) {
    const float* user_emb = (const float*)d_in[0];
    const float* item_emb = (const float*)d_in[1];
    const int*   adj_rows = (const int*)d_in[2];
    const int*   adj_cols = (const int*)d_in[3];
    const float* adj_vals = (const float*)d_in[4];

    const int n_users = in_sizes[0] / EMB;
    const int n_items = in_sizes[1] / EMB;
    const int nnz     = in_sizes[2];
    const int n       = n_users + n_items;

    char* ws = (char*)d_ws;
    size_t xbytes  = (size_t)n * EMB * sizeof(u16);                 // 38.4 MB
    size_t pebytes = ((size_t)nnz + 16 * (size_t)n) * sizeof(int2); // 62.4 MB
    u32*  x0 = (u32*)ws;
    u32*  y1 = (u32*)(ws + xbytes);
    u32*  y2 = (u32*)(ws + 2 * xbytes);
    int2* pe = (int2*)(ws + 3 * xbytes);
    int*  row_ptr = (int*)(ws + 3 * xbytes + pebytes);

    int nvec = n * (EMB / 4);

    // x0 (bf16) = concat(user, item)
    init_x_kernel<<<(nvec + 255) / 256, 256, 0, stream>>>(
        (const float4*)user_emb, (const float4*)item_emb,
        (ushort4*)x0, n_users * (EMB / 4), nvec);

    // CSR row pointers from sorted rows
    build_row_ptr_kernel<<<(n + 1 + 255) / 256, 256, 0, stream>>>(
        adj_rows, nnz, n, row_ptr);

    // padded edge array {byte_off, val}, pad to multiple of 16
    expand_kernel<<<(nnz + 255) / 256, 256, 0, stream>>>(
        adj_rows, adj_cols, adj_vals, row_ptr, nnz, pe);

    // layers 1,2 -> bf16 y; layer 3 fused with mean epilogue -> fp32 out
    int wg_blocks = (n + 3) / 4;
    spmm_kernel<<<wg_blocks, 256, 0, stream>>>(row_ptr, pe, x0, y1, n);
    spmm_kernel<<<wg_blocks, 256, 0, stream>>>(row_ptr, pe, y1, y2, n);
    spmm_final_kernel<<<wg_blocks, 256, 0, stream>>>(
        row_ptr, pe, x0, y1, y2, (float4*)d_out, n);
}

// Round 7
// 268.905 us; speedup vs baseline: 1.3296x; 1.3296x over previous
//
#include <hip/hip_runtime.h>
#include <hip/hip_bf16.h>

// LightGCN forward: x0 = concat(user_emb, item_emb); 3x { x = A*x }; out = (x0+x1+x2+x3)/4.
// Sorted COO -> CSR row_ptr (binary search). Edges pre-expanded into a PADDED
// array pe[]: row r's segment starts at row_ptr[r] + 4*r (capacity deg+4),
// entry = {byte offset col*128, val fp32}, zero-padded to multiple of 4.
// SpMM: one 8-LANE GROUP per row; lane holds 8 dims (one dwordx4 = whole 128B
// bf16 row per gather). 8 independent rows per wave -> up to 32 outstanding
// gathers/wave, no cross-lane reduce, 8x fewer waves. Layer 3 fused with mean.

#define EMB 64

typedef unsigned short u16;
typedef unsigned int   u32;

__device__ __forceinline__ u16 f2bf(float f) {      // round-to-nearest-even
    u32 u = __float_as_uint(f);
    return (u16)((u + 0x7FFFu + ((u >> 16) & 1u)) >> 16);
}
__device__ __forceinline__ float bflo(u32 p) { return __uint_as_float(p << 16); }
__device__ __forceinline__ float bfhi(u32 p) { return __uint_as_float(p & 0xFFFF0000u); }
__device__ __forceinline__ u32 pack2(float hi, float lo) {
    return ((u32)f2bf(hi) << 16) | (u32)f2bf(lo);
}

__global__ void init_x_kernel(const float4* __restrict__ user,
                              const float4* __restrict__ item,
                              ushort4* __restrict__ x,
                              int n_user_vec, int n_total_vec) {
    int i = blockIdx.x * blockDim.x + threadIdx.x;
    if (i >= n_total_vec) return;
    float4 v = (i < n_user_vec) ? user[i] : item[i - n_user_vec];
    ushort4 o;
    o.x = f2bf(v.x); o.y = f2bf(v.y); o.z = f2bf(v.z); o.w = f2bf(v.w);
    x[i] = o;
}

// row_ptr[r] = lower_bound(rows, r); rows sorted.
__global__ void build_row_ptr_kernel(const int* __restrict__ rows, int nnz,
                                     int n_rows, int* __restrict__ row_ptr) {
    int r = blockIdx.x * blockDim.x + threadIdx.x;
    if (r > n_rows) return;
    int lo = 0, hi = nnz;
    while (lo < hi) {
        int mid = (lo + hi) >> 1;
        if (rows[mid] < r) lo = mid + 1; else hi = mid;
    }
    row_ptr[r] = lo;
}

// pe[e + 4*rows[e]] = {cols[e]*128, vals[e]}; last edge of each row zero-fills
// the <=3 pad slots up to the row's ceil4(deg) boundary.
__global__ void expand_kernel(const int* __restrict__ rows,
                              const int* __restrict__ cols,
                              const float* __restrict__ vals,
                              const int* __restrict__ row_ptr,
                              int nnz, int2* __restrict__ pe) {
    int e = blockIdx.x * blockDim.x + threadIdx.x;
    if (e >= nnz) return;
    int r = rows[e];
    int dst = e + 4 * r;
    int2 ent;
    ent.x = cols[e] << 7;                    // byte offset into bf16 x table
    ent.y = __float_as_int(vals[e]);
    pe[dst] = ent;
    bool last = (e == nnz - 1) || (rows[e + 1] != r);
    if (last) {
        int s   = row_ptr[r];
        int deg = e + 1 - s;
        int cnt = (deg + 3) & ~3;
        int lim = s + 4 * r + cnt;           // segment start + padded count
        int2 z; z.x = 0; z.y = 0;
        for (int j = dst + 1; j < lim; ++j) pe[j] = z;
    }
}

// Core row accumulate for one 8-lane group. lane sub holds dims 8sub..8sub+7.
__device__ __forceinline__ void spmm_row8(const int2* __restrict__ pe,
                                          const char* __restrict__ xb,
                                          int ps, int cnt, u32 lane_byte,
                                          float* a /*[8]*/) {
#pragma unroll
    for (int k = 0; k < 8; ++k) a[k] = 0.0f;
    for (int j = 0; j < cnt; j += 4) {
        int2 ent[4];
#pragma unroll
        for (int k = 0; k < 4; ++k)
            ent[k] = pe[ps + j + k];          // 8 same-addr lanes -> 1 req
        uint4 xp[4];
#pragma unroll
        for (int k = 0; k < 4; ++k)
            xp[k] = *(const uint4*)(xb + ((u32)ent[k].x + lane_byte));
#pragma unroll
        for (int k = 0; k < 4; ++k) {
            float v = __int_as_float(ent[k].y);
            a[0] = fmaf(v, bflo(xp[k].x), a[0]);
            a[1] = fmaf(v, bfhi(xp[k].x), a[1]);
            a[2] = fmaf(v, bflo(xp[k].y), a[2]);
            a[3] = fmaf(v, bfhi(xp[k].y), a[3]);
            a[4] = fmaf(v, bflo(xp[k].z), a[4]);
            a[5] = fmaf(v, bfhi(xp[k].z), a[5]);
            a[6] = fmaf(v, bflo(xp[k].w), a[6]);
            a[7] = fmaf(v, bfhi(xp[k].w), a[7]);
        }
    }
}

__global__ void spmm_kernel(const int* __restrict__ row_ptr,
                            const int2* __restrict__ pe,
                            const u32* __restrict__ x,    // bf16x2 table [n*32]
                            uint4* __restrict__ y,        // bf16 rows as uint4 [n*8]
                            int n_rows) {
    int tid = blockIdx.x * blockDim.x + threadIdx.x;
    int row = tid >> 3;
    int sub = threadIdx.x & 7;
    if (row >= n_rows) return;

    int s   = row_ptr[row];
    int deg = row_ptr[row + 1] - s;
    int cnt = (deg + 3) & ~3;
    int ps  = s + 4 * row;

    float a[8];
    spmm_row8(pe, (const char*)x, ps, cnt, (u32)sub * 16u, a);

    uint4 w;
    w.x = pack2(a[1], a[0]);
    w.y = pack2(a[3], a[2]);
    w.z = pack2(a[5], a[4]);
    w.w = pack2(a[7], a[6]);
    y[(size_t)row * 8 + sub] = w;
}

// Layer 3 fused with epilogue: out = (x0 + y1 + y2 + A*y2) * 0.25 (fp32 out).
__global__ void spmm_final_kernel(const int* __restrict__ row_ptr,
                                  const int2* __restrict__ pe,
                                  const uint4* __restrict__ x0,   // bf16 rows [n*8]
                                  const uint4* __restrict__ y1,
                                  const uint4* __restrict__ y2,   // also gather src
                                  float4* __restrict__ out,       // [n*16]
                                  int n_rows) {
    int tid = blockIdx.x * blockDim.x + threadIdx.x;
    int row = tid >> 3;
    int sub = threadIdx.x & 7;
    if (row >= n_rows) return;

    int s   = row_ptr[row];
    int deg = row_ptr[row + 1] - s;
    int cnt = (deg + 3) & ~3;
    int ps  = s + 4 * row;

    float a[8];
    spmm_row8(pe, (const char*)y2, ps, cnt, (u32)sub * 16u, a);

    size_t i8 = (size_t)row * 8 + sub;
    uint4 b0 = x0[i8], b1 = y1[i8], b2 = y2[i8];
    float4 r0, r1;
    r0.x = (bflo(b0.x) + bflo(b1.x) + bflo(b2.x) + a[0]) * 0.25f;
    r0.y = (bfhi(b0.x) + bfhi(b1.x) + bfhi(b2.x) + a[1]) * 0.25f;
    r0.z = (bflo(b0.y) + bflo(b1.y) + bflo(b2.y) + a[2]) * 0.25f;
    r0.w = (bfhi(b0.y) + bfhi(b1.y) + bfhi(b2.y) + a[3]) * 0.25f;
    r1.x = (bflo(b0.z) + bflo(b1.z) + bflo(b2.z) + a[4]) * 0.25f;
    r1.y = (bfhi(b0.z) + bfhi(b1.z) + bfhi(b2.z) + a[5]) * 0.25f;
    r1.z = (bflo(b0.w) + bflo(b1.w) + bflo(b2.w) + a[6]) * 0.25f;
    r1.w = (bfhi(b0.w) + bfhi(b1.w) + bfhi(b2.w) + a[7]) * 0.25f;
    size_t o4 = (size_t)row * 16 + (size_t)sub * 2;
    out[o4]     = r0;
    out[o4 + 1] = r1;
}

extern "C" void kernel_launch(void* const* d_in, const int* in_sizes, int n_in,
                              void* d_out, int out_size, void* d_ws, size_t ws_size,
                              hipStream_t stream) {
    const float* user_emb = (const float*)d_in[0];
    const float* item_emb = (const float*)d_in[1];
    const int*   adj_rows = (const int*)d_in[2];
    const int*   adj_cols = (const int*)d_in[3];
    const float* adj_vals = (const float*)d_in[4];

    const int n_users = in_sizes[0] / EMB;
    const int n_items = in_sizes[1] / EMB;
    const int nnz     = in_sizes[2];
    const int n       = n_users + n_items;

    char* ws = (char*)d_ws;
    size_t xbytes  = (size_t)n * EMB * sizeof(u16);                // 38.4 MB
    size_t pebytes = ((size_t)nnz + 4 * (size_t)n) * sizeof(int2); // 33.6 MB
    u32*  x0 = (u32*)ws;
    u32*  y1 = (u32*)(ws + xbytes);
    u32*  y2 = (u32*)(ws + 2 * xbytes);
    int2* pe = (int2*)(ws + 3 * xbytes);
    int*  row_ptr = (int*)(ws + 3 * xbytes + pebytes);

    int nvec = n * (EMB / 4);

    // x0 (bf16) = concat(user, item)
    init_x_kernel<<<(nvec + 255) / 256, 256, 0, stream>>>(
        (const float4*)user_emb, (const float4*)item_emb,
        (ushort4*)x0, n_users * (EMB / 4), nvec);

    // CSR row pointers from sorted rows
    build_row_ptr_kernel<<<(n + 1 + 255) / 256, 256, 0, stream>>>(
        adj_rows, nnz, n, row_ptr);

    // padded edge array {byte_off, val}, pad to multiple of 4
    expand_kernel<<<(nnz + 255) / 256, 256, 0, stream>>>(
        adj_rows, adj_cols, adj_vals, row_ptr, nnz, pe);

    // layers 1,2 -> bf16 y; layer 3 fused with mean epilogue -> fp32 out
    int blocks = (n * 8 + 255) / 256;   // 8 lanes per row, 32 rows per block
    spmm_kernel<<<blocks, 256, 0, stream>>>(row_ptr, pe, x0, (uint4*)y1, n);
    spmm_kernel<<<blocks, 256, 0, stream>>>(row_ptr, pe, y1, (uint4*)y2, n);
    spmm_final_kernel<<<blocks, 256, 0, stream>>>(
        row_ptr, pe, (const uint4*)x0, (const uint4*)y1, (const uint4*)y2,
        (float4*)d_out, n);
}